// Round 1
// baseline (306.301 us; speedup 1.0000x reference)
//
#include <hip/hip_runtime.h>

// Problem constants (from reference)
#define BATCH   64
#define SEQ     1534
#define C_IN    21
#define DM      516
#define NJ      129      // DM / 4 (float4 chunks per row)
#define KS      8
#define NK      74
#define PADL    21

// Each thread: fixed (b, ch, j). Loads a 17-tap x window covering d in [4j,4j+4),
// then emits rows i = n*21+ch for n = 0..72 (+ n=73 fin row when ch==0).
// Lanes consecutive in j -> coalesced float4 loads (pe, tables) and stores (out).
__global__ __launch_bounds__(256) void embed_kernel(
    const float* __restrict__ x,
    const int*   __restrict__ xm,
    const float* __restrict__ kernels,
    const float* __restrict__ pe,
    const float* __restrict__ hour_tab,
    const float* __restrict__ weekday_tab,
    const float* __restrict__ day_tab,
    const float* __restrict__ month_tab,
    float*       __restrict__ out)
{
    __shared__ float sk[NK * KS];   // 592 floats = 2.4 KB
    for (int t = threadIdx.x; t < NK * KS; t += blockDim.x) sk[t] = kernels[t];
    __syncthreads();

    const int tid   = blockIdx.x * blockDim.x + threadIdx.x;
    const int total = BATCH * C_IN * NJ;
    if (tid >= total) return;

    const int j    = tid % NJ;
    const int rest = tid / NJ;
    const int ch   = rest % C_IN;
    const int b    = rest / C_IN;

    // 17-tap x window: t = 12j - 21 + s, s in [0,17)
    float w[17];
    const int t0 = 12 * j - PADL;
#pragma unroll
    for (int s = 0; s < 17; ++s) {
        const int t = t0 + s;
        w[s] = (t >= 0 && t < SEQ) ? x[(b * SEQ + t) * C_IN + ch] : 0.0f;
    }

    const float4* pe4 = (const float4*)pe;
    const float4* h4  = (const float4*)hour_tab;
    const float4* wd4 = (const float4*)weekday_tab;
    const float4* dy4 = (const float4*)day_tab;
    const float4* mo4 = (const float4*)month_tab;
    float4*       o4  = (float4*)out;

    const long long bSEQ = (long long)b * SEQ;
    const int nrows = (ch == 0) ? NK : (NK - 1);   // ch==0 also owns the fin row (i=1533, kernel row 73)

    for (int n = 0; n < nrows; ++n) {
        const int i = n * C_IN + ch;               // fin: 73*21+0 = 1533 — uniform formula

        // tok: 8-tap conv for 4 consecutive d
        float acc[4];
#pragma unroll
        for (int dd = 0; dd < 4; ++dd) {
            float a = 0.0f;
#pragma unroll
            for (int k = 0; k < KS; ++k) a += w[3 * dd + k] * sk[n * KS + k];
            acc[dd] = a;
        }

        // temporal embedding lookups (wave-uniform addresses -> broadcast)
        const int* xr = xm + (bSEQ + i) * 5;
        const int hi = xr[3], wi = xr[2], di = xr[1], mi = xr[0];

        const float4 p  = pe4[i * NJ + j];
        const float4 th = h4 [hi * NJ + j];
        const float4 tw = wd4[wi * NJ + j];
        const float4 td = dy4[di * NJ + j];
        const float4 tm = mo4[mi * NJ + j];

        float4 o;
        o.x = acc[0] + p.x + th.x + tw.x + td.x + tm.x;
        o.y = acc[1] + p.y + th.y + tw.y + td.y + tm.y;
        o.z = acc[2] + p.z + th.z + tw.z + td.z + tm.z;
        o.w = acc[3] + p.w + th.w + tw.w + td.w + tm.w;

        o4[(bSEQ + i) * NJ + j] = o;
    }
}

extern "C" void kernel_launch(void* const* d_in, const int* in_sizes, int n_in,
                              void* d_out, int out_size, void* d_ws, size_t ws_size,
                              hipStream_t stream) {
    const float* x        = (const float*)d_in[0];
    const int*   x_mark   = (const int*)  d_in[1];
    const float* kernels  = (const float*)d_in[2];
    const float* pe       = (const float*)d_in[3];
    const float* hour_tab = (const float*)d_in[4];
    const float* wday_tab = (const float*)d_in[5];
    const float* day_tab  = (const float*)d_in[6];
    const float* mon_tab  = (const float*)d_in[7];
    float*       out      = (float*)d_out;

    const int total  = BATCH * C_IN * NJ;          // 173,376 threads
    const int blocks = (total + 255) / 256;        // 678 blocks
    embed_kernel<<<blocks, 256, 0, stream>>>(
        x, x_mark, kernels, pe, hour_tab, wday_tab, day_tab, mon_tab, out);
}

// Round 2
// 297.819 us; speedup vs baseline: 1.0285x; 1.0285x over previous
//
#include <hip/hip_runtime.h>

// Problem constants (from reference)
#define BATCH   64
#define SEQ     1534
#define C_IN    21
#define DM      516
#define NJ      129      // DM / 4 (float4 chunks per row)
#define KS      8
#define NK      74
#define PADL    21
#define NSPLIT  4        // n-loop split factor (occupancy)

// Thread = (b, ch, s, j). Loads a 17-tap x window covering d in [4j,4j+4),
// emits rows i = n*21+ch for n = s, s+4, ... (fin row i=1533 == n=73,ch=0).
// Lanes consecutive in j -> coalesced float4 loads (pe, tables) and stores.
// s is a fast dim in the flat tid so the 4 window-duplicate threads dispatch
// in adjacent blocks and share L2/L3 for the x window lines.
__global__ __launch_bounds__(256) void embed_kernel(
    const float* __restrict__ x,
    const int*   __restrict__ xm,
    const float* __restrict__ kernels,
    const float* __restrict__ pe,
    const float* __restrict__ hour_tab,
    const float* __restrict__ weekday_tab,
    const float* __restrict__ day_tab,
    const float* __restrict__ month_tab,
    float*       __restrict__ out)
{
    __shared__ float sk[NK * KS];   // 592 floats = 2.4 KB
    for (int t = threadIdx.x; t < NK * KS; t += blockDim.x) sk[t] = kernels[t];
    __syncthreads();

    const int tid = blockIdx.x * blockDim.x + threadIdx.x;
    // tid = ((b*C_IN + ch) * NSPLIT + s) * NJ + j
    const int j     = tid % NJ;
    const int rest  = tid / NJ;
    const int s     = rest % NSPLIT;
    const int bc    = rest / NSPLIT;
    const int ch    = bc % C_IN;
    const int b     = bc / C_IN;

    // 17-tap x window: t = 12j - 21 + u, u in [0,17)
    float w[17];
    const int t0 = 12 * j - PADL;
#pragma unroll
    for (int u = 0; u < 17; ++u) {
        const int t = t0 + u;
        w[u] = (t >= 0 && t < SEQ) ? x[(b * SEQ + t) * C_IN + ch] : 0.0f;
    }

    const float4* pe4 = (const float4*)pe;
    const float4* h4  = (const float4*)hour_tab;
    const float4* wd4 = (const float4*)weekday_tab;
    const float4* dy4 = (const float4*)day_tab;
    const float4* mo4 = (const float4*)month_tab;
    float4*       o4  = (float4*)out;

    const int bSEQ = b * SEQ;

    for (int n = s; n < NK; n += NSPLIT) {
        if (n == NK - 1 && ch != 0) continue;      // fin row only exists for ch==0
        const int i = n * C_IN + ch;               // fin: 73*21+0 = 1533

        // tok: 8-tap conv for 4 consecutive d
        float acc[4];
#pragma unroll
        for (int dd = 0; dd < 4; ++dd) {
            float a = 0.0f;
#pragma unroll
            for (int k = 0; k < KS; ++k) a += w[3 * dd + k] * sk[n * KS + k];
            acc[dd] = a;
        }

        // temporal embedding lookups (wave-uniform addresses -> broadcast)
        const int* xr = xm + (bSEQ + i) * 5;
        const int hi = xr[3], wi = xr[2], di = xr[1], mi = xr[0];

        const float4 p  = pe4[i * NJ + j];
        const float4 th = h4 [hi * NJ + j];
        const float4 tw = wd4[wi * NJ + j];
        const float4 td = dy4[di * NJ + j];
        const float4 tm = mo4[mi * NJ + j];

        float4 o;
        o.x = acc[0] + p.x + th.x + tw.x + td.x + tm.x;
        o.y = acc[1] + p.y + th.y + tw.y + td.y + tm.y;
        o.z = acc[2] + p.z + th.z + tw.z + td.z + tm.z;
        o.w = acc[3] + p.w + th.w + tw.w + td.w + tm.w;

        o4[(bSEQ + i) * NJ + j] = o;
    }
}

extern "C" void kernel_launch(void* const* d_in, const int* in_sizes, int n_in,
                              void* d_out, int out_size, void* d_ws, size_t ws_size,
                              hipStream_t stream) {
    const float* x        = (const float*)d_in[0];
    const int*   x_mark   = (const int*)  d_in[1];
    const float* kernels  = (const float*)d_in[2];
    const float* pe       = (const float*)d_in[3];
    const float* hour_tab = (const float*)d_in[4];
    const float* wday_tab = (const float*)d_in[5];
    const float* day_tab  = (const float*)d_in[6];
    const float* mon_tab  = (const float*)d_in[7];
    float*       out      = (float*)d_out;

    const int total  = BATCH * C_IN * NSPLIT * NJ; // 693,504 threads
    const int blocks = (total + 255) / 256;        // 2709 blocks exactly
    embed_kernel<<<blocks, 256, 0, stream>>>(
        x, x_mark, kernels, pe, hour_tab, wday_tab, day_tab, mon_tab, out);
}

// Round 3
// 283.789 us; speedup vs baseline: 1.0793x; 1.0494x over previous
//
#include <hip/hip_runtime.h>

// Problem constants (from reference)
#define BATCH   64
#define SEQ     1534
#define C_IN    21
#define DM      516
#define NJ      129      // DM / 4 (float4 chunks per row)
#define KS      8
#define NK      74
#define PADL    21
#define NSPLIT  4        // n-loop split factor (occupancy)
#define JW      12       // j-chunk per block
#define NBJ     11       // ceil(NJ / JW)
#define TSPAN   (12*(JW-1) + 17)   // 149 taps cover jj in [0,JW)

// Block = (b, jb, s). Stage x[b, t0:t0+TSPAN, :] into LDS (coalesced,
// zero-padded), then thread (ch, jj) reads its 17 taps from LDS into
// registers and emits rows i = n*21+ch for n = s, s+NSPLIT, ...
__global__ __launch_bounds__(256) void embed_kernel(
    const float* __restrict__ x,
    const int*   __restrict__ xm,
    const float* __restrict__ kernels,
    const float* __restrict__ pe,
    const float* __restrict__ hour_tab,
    const float* __restrict__ weekday_tab,
    const float* __restrict__ day_tab,
    const float* __restrict__ month_tab,
    float*       __restrict__ out)
{
    __shared__ float sk[NK * KS];        // 592 floats
    __shared__ float sx[TSPAN * C_IN];   // 3129 floats = 12.5 KB

    // decode block: bid = ((b*NBJ + jb)*NSPLIT + s)
    const int bid = blockIdx.x;
    const int s   = bid % NSPLIT;
    const int t1  = bid / NSPLIT;
    const int jb  = t1 % NBJ;
    const int b   = t1 / NBJ;
    const int j0  = jb * JW;
    const int t0  = 12 * j0 - PADL;      // first tap (may be negative)

    for (int t = threadIdx.x; t < NK * KS; t += 256) sk[t] = kernels[t];

    // Stage x slab: flat floats p in [0, TSPAN*21), global = x[(b*SEQ+t0)*21 + p],
    // zero when t < 0 or t >= SEQ  <=>  p < -t0*21 or p >= (SEQ-t0)*21.
    {
        const int base = (b * SEQ + t0) * C_IN;
        const int lo   = -t0 * C_IN;
        const int hi   = (SEQ - t0) * C_IN;
        for (int p = threadIdx.x; p < TSPAN * C_IN; p += 256) {
            float v = 0.0f;
            if (p >= lo && p < hi) v = x[base + p];
            sx[p] = v;
        }
    }
    __syncthreads();

    const int ch = threadIdx.x / JW;
    const int jj = threadIdx.x % JW;
    const int j  = j0 + jj;
    if (ch >= C_IN || j >= NJ) return;

    // 17 taps for d in [4j, 4j+4): t = 12j - 21 + u  ->  LDS (12jj+u)*21 + ch
    float w[17];
#pragma unroll
    for (int u = 0; u < 17; ++u) w[u] = sx[(12 * jj + u) * C_IN + ch];

    const float4* pe4 = (const float4*)pe;
    const float4* h4  = (const float4*)hour_tab;
    const float4* wd4 = (const float4*)weekday_tab;
    const float4* dy4 = (const float4*)day_tab;
    const float4* mo4 = (const float4*)month_tab;
    float4*       o4  = (float4*)out;

    const int bSEQ = b * SEQ;

    for (int n = s; n < NK; n += NSPLIT) {
        if (n == NK - 1 && ch != 0) continue;   // fin row (i=1533) only for ch==0
        const int i = n * C_IN + ch;

        float acc[4];
#pragma unroll
        for (int dd = 0; dd < 4; ++dd) {
            float a = 0.0f;
#pragma unroll
            for (int k = 0; k < KS; ++k) a += w[3 * dd + k] * sk[n * KS + k];
            acc[dd] = a;
        }

        const int* xr = xm + (bSEQ + i) * 5;
        const int hi = xr[3], wi = xr[2], di = xr[1], mi = xr[0];

        const float4 p  = pe4[i * NJ + j];
        const float4 th = h4 [hi * NJ + j];
        const float4 tw = wd4[wi * NJ + j];
        const float4 td = dy4[di * NJ + j];
        const float4 tm = mo4[mi * NJ + j];

        float4 o;
        o.x = acc[0] + p.x + th.x + tw.x + td.x + tm.x;
        o.y = acc[1] + p.y + th.y + tw.y + td.y + tm.y;
        o.z = acc[2] + p.z + th.z + tw.z + td.z + tm.z;
        o.w = acc[3] + p.w + th.w + tw.w + td.w + tm.w;

        o4[(bSEQ + i) * NJ + j] = o;
    }
}

extern "C" void kernel_launch(void* const* d_in, const int* in_sizes, int n_in,
                              void* d_out, int out_size, void* d_ws, size_t ws_size,
                              hipStream_t stream) {
    const float* x        = (const float*)d_in[0];
    const int*   x_mark   = (const int*)  d_in[1];
    const float* kernels  = (const float*)d_in[2];
    const float* pe       = (const float*)d_in[3];
    const float* hour_tab = (const float*)d_in[4];
    const float* wday_tab = (const float*)d_in[5];
    const float* day_tab  = (const float*)d_in[6];
    const float* mon_tab  = (const float*)d_in[7];
    float*       out      = (float*)d_out;

    const int blocks = BATCH * NBJ * NSPLIT;   // 64*11*4 = 2816
    embed_kernel<<<blocks, 256, 0, stream>>>(
        x, x_mark, kernels, pe, hour_tab, wday_tab, day_tab, mon_tab, out);
}